// Round 17
// baseline (684.231 us; speedup 1.0000x reference)
//
#include <hip/hip_runtime.h>

#define DD 128
#define BSZ 128
#define SEQL 128
#define TST 127
#define QNN 4
#define CNN 10
#define NQCC 4
#define RKK 10
#define NEGV -1000000000.0f

// ---- workspace float offsets ----
#define OFF_WTA0    0
#define OFF_WTA1    16384
#define OFF_WTAL    32768
#define OFF_WTIH1A  49152
#define OFF_ERIH1   98304
#define OFF_MT      99072
#define OFF_WPACK   115456
#define OFF_ECA0    189184
#define OFF_E1C     317184
#define OFF_KQC     445184
#define OFF_VQCC    509184
#define OFF_KBC     510184
#define OFF_U       511184
#define OFF_W2      511312
#define OFF_C0      511440
#define OFF_GI1     511488
#define OFF_KQ0     6753792
#define OFF_VQC0    7802368
#define OFF_KB0     7818752
#define OFF_TIX     7835136
#define OFF_TMSK    7997696
#define OFF_CID     8160256

// padded f32 x index: chunk stride 36 floats
#define XI(e) ((e) + (((e) >> 5) << 2))
// packed f16 x: chunk stride 40 halfwords (80B, 16B-aligned)
#define PH(e) ((((e) >> 5) * 40) + ((e) & 31))
#define PU(e) ((((e) >> 5) * 20) + (((e) & 31) >> 1))

typedef __fp16 h2 __attribute__((ext_vector_type(2)));

__device__ __forceinline__ float sigm(float x) { return 1.0f / (1.0f + __expf(-x)); }
// fast tanh: (1-e^{-2|x|})/(1+e^{-2|x|}) with sign
__device__ __forceinline__ float ftanh(float x) {
  float ax = fabsf(x);
  float T = __expf(-2.f * ax);
  float r = (1.f - T) * __builtin_amdgcn_rcpf(1.f + T);
  return copysignf(r, x);
}
__device__ __forceinline__ unsigned pkh(float a, float b) {
  h2 v; v.x = (__fp16)a; v.y = (__fp16)b;
  return __builtin_bit_cast(unsigned, v);
}
__device__ __forceinline__ float fd2u(float acc, unsigned w, unsigned x) {
  return __builtin_amdgcn_fdot2(__builtin_bit_cast(h2, w), __builtin_bit_cast(h2, x), acc, false);
}
// raw barrier: LDS drained, global loads stay in flight
__device__ __forceinline__ void bar() {
  asm volatile("s_waitcnt lgkmcnt(0)" ::: "memory");
  __builtin_amdgcn_s_barrier();
  asm volatile("" ::: "memory");
}

// ---------------- K0a: tables + WPACK (blocks 0..674)  |  mqk (blocks 675..804) ----------------
__global__ __launch_bounds__(256) void k_prep(
    const float* __restrict__ W_hh1, const float* __restrict__ W_ih2,
    const float* __restrict__ W_hh2, const float* __restrict__ W_agg,
    const float* __restrict__ W_agg_last, const float* __restrict__ W_ih1,
    const float* __restrict__ Er, const float* __restrict__ Wq,
    const float* __restrict__ Wk, const float* __restrict__ bq,
    const float* __restrict__ bk, float* __restrict__ ws) {
  int tid = threadIdx.x;
  if (blockIdx.x < 675) {
    int idx = blockIdx.x * 256 + tid;
    const int TOT = 172800;
    for (int o = idx; o < TOT; o += 675 * 256) {
      int r = o;
      if (r < 16384) { int j = r >> 7, i = r & 127; ws[OFF_WTA0 + r] = W_agg[i * 128 + j]; continue; }
      r -= 16384;
      if (r < 16384) { int j = r >> 7, i = r & 127; ws[OFF_WTA1 + r] = W_agg[16384 + i * 128 + j]; continue; }
      r -= 16384;
      if (r < 16384) { int j = r >> 7, i = r & 127; ws[OFF_WTAL + r] = W_agg_last[i * 128 + j]; continue; }
      r -= 16384;
      if (r < 49152) { int j = r / 384, i = r % 384; ws[OFF_WTIH1A + r] = W_ih1[i * 256 + j]; continue; }
      r -= 49152;
      if (r < 768) {
        int rr = r / 384, i2 = r % 384;
        float a = 0.f;
        for (int j = 0; j < 128; ++j) a += Er[rr * 128 + j] * W_ih1[i2 * 256 + 128 + j];
        ws[OFF_ERIH1 + r] = a; continue;
      }
      r -= 768;
      {
        int n = r & 3; int q = r >> 2;
        int i = q & 127; q >>= 7;
        int kk = q & 3; q >>= 2;
        int jc = q & 3; int c = q >> 2;
        int j0 = jc * 32 + kk * 8 + n * 2;
        const float* row;
        if (c < 3) row = W_hh1 + (size_t)(c * 128 + i) * 128;
        else if (c < 6) row = W_ih2 + (size_t)((c - 3) * 128 + i) * 128;
        else row = W_hh2 + (size_t)((c - 6) * 128 + i) * 128;
        ((unsigned*)ws)[OFF_WPACK + r] = pkh(row[j0], row[j0 + 1]);
      }
    }
  } else {
    int j = blockIdx.x - 675;
    __shared__ float wkc[128];
    __shared__ float sc[128];
    if (j < 128) {
      if (tid < 128) wkc[tid] = Wk[tid * 128 + j];
      __syncthreads();
      if (tid < 128) {
        float a = 0.f;
        for (int l = 0; l < 128; ++l) a = fmaf(Wq[l * 128 + tid], wkc[l], a);
        ws[OFF_MT + j * 128 + tid] = a;
      }
    } else if (j == 128) {
      if (tid < 128) {
        float a = 0.f;
        for (int l = 0; l < 128; ++l) a = fmaf(Wq[l * 128 + tid], bk[l], a);
        ws[OFF_U + tid] = a;
      }
    } else {
      if (tid < 128) {
        float a = 0.f;
        for (int l = 0; l < 128; ++l) a = fmaf(bq[l], Wk[l * 128 + tid], a);
        ws[OFF_W2 + tid] = a;
        sc[tid] = bq[tid] * bk[tid];
      }
      __syncthreads();
      if (tid == 0) { float s = 0.f; for (int l = 0; l < 128; ++l) s += sc[l]; ws[OFF_C0] = s; }
    }
  }
}

// ---------------- K0b: per-concept tables ----------------
__global__ __launch_bounds__(128) void k_concept(
    const int* __restrict__ cnbr, const float* __restrict__ Eq,
    const float* __restrict__ Ec, const float* __restrict__ b_agg,
    const float* __restrict__ Ww, float* __restrict__ ws) {
  int c = blockIdx.x;
  int tid = threadIdx.x;
  __shared__ int s_nb[CNN];
  __shared__ float s_v[DD], s_ec[DD], s_t2[DD], s_w2[DD], s_kb2[DD];
  if (tid < CNN) s_nb[tid] = cnbr[c * CNN + tid];
  __syncthreads();
  float ec = Ec[c * DD + tid];
  float cm = 0.f;
#pragma unroll
  for (int l = 0; l < CNN; ++l) cm += Eq[(size_t)s_nb[l] * DD + tid];
  s_ec[tid] = ec;
  s_v[tid] = cm * 0.1f + ec;
  __syncthreads();
  const float* WtA0 = ws + OFF_WTA0;
  const float* WtA1 = ws + OFF_WTA1;
  const float* MT = ws + OFF_MT;
  float a1 = 0.f, a0 = 0.f, kq = 0.f;
#pragma unroll 8
  for (int j = 0; j < DD; ++j) {
    a1 += WtA1[j * DD + tid] * s_v[j];
    a0 += WtA0[j * DD + tid] * s_ec[j];
    kq += MT[j * DD + tid] * s_ec[j];
  }
  ws[OFF_E1C + c * DD + tid] = ftanh(a1 + b_agg[DD + tid]);
  ws[OFF_ECA0 + c * DD + tid] = a0;
  s_t2[tid] = kq + ws[OFF_U + tid];
  s_w2[tid] = s_ec[tid] * Ww[128 + tid];
  s_kb2[tid] = s_ec[tid] * ws[OFF_W2 + tid];
  __syncthreads();
  if (tid < 64) {
    ((unsigned*)ws)[OFF_KQC + c * 64 + tid] = pkh(s_t2[2 * tid], s_t2[2 * tid + 1]);
    float pa = s_w2[tid] + s_w2[tid + 64];
    float pb = s_kb2[tid] + s_kb2[tid + 64];
    for (int off = 32; off > 0; off >>= 1) { pa += __shfl_down(pa, off); pb += __shfl_down(pb, off); }
    if (tid == 0) { ws[OFF_VQCC + c] = pa; ws[OFF_KBC + c] = pb + ws[OFF_C0]; }
  }
}

// ---- K1: blocks 0..127 Gram(b)+top-10(in-LDS) ; blocks 128..255 KQ0/vqc0/kb0/cid ----
__global__ __launch_bounds__(256) void k_gram(
    const int* __restrict__ qseq, const int* __restrict__ qctab,
    const float* __restrict__ Eq, const float* __restrict__ Ww,
    float* __restrict__ ws) {
  int role = blockIdx.x >> 7;
  int b = blockIdx.x & 127;
  int tid = threadIdx.x;
  int lane = tid & 63, wv = tid >> 6;
  __shared__ float sX[128][129];
  __shared__ int sq[SEQL];
  if (tid < 128) sq[tid] = qseq[b * SEQL + tid];
  __syncthreads();
  for (int o = tid; o < 128 * 32; o += 256) {
    int s = o >> 5, p = o & 31;
    float4 v = ((const float4*)(Eq + (size_t)sq[s] * DD))[p];
    sX[s][p * 4] = v.x; sX[s][p * 4 + 1] = v.y; sX[s][p * 4 + 2] = v.z; sX[s][p * 4 + 3] = v.w;
  }
  __syncthreads();
  if (role == 0) {
    // Gram in registers
    __shared__ float sGram[128][130];
    int r0 = (tid >> 4) * 8, c0 = (tid & 15) * 8;
    float acc[8][8];
#pragma unroll
    for (int u = 0; u < 8; ++u)
#pragma unroll
      for (int v = 0; v < 8; ++v) acc[u][v] = 0.f;
    for (int k = 0; k < 128; ++k) {
      float a[8], bb[8];
#pragma unroll
      for (int u = 0; u < 8; ++u) { a[u] = sX[r0 + u][k]; bb[u] = sX[c0 + u][k]; }
#pragma unroll
      for (int u = 0; u < 8; ++u)
#pragma unroll
        for (int v = 0; v < 8; ++v) acc[u][v] = fmaf(a[u], bb[v], acc[u][v]);
    }
#pragma unroll
    for (int u = 0; u < 8; ++u)
#pragma unroll
      for (int v = 0; v < 8; ++v) sGram[r0 + u][c0 + v] = acc[u][v];
    __syncthreads();
    // top-10 per t, wave wv handles t = wv, wv+4, ...
    int* tix = (int*)(ws + OFF_TIX);
    int* tmsk = (int*)(ws + OFF_TMSK);
    for (int t = wv; t < TST; t += 4) {
      const float* grow = sGram[t + 1];
      float v0 = (lane < t) ? grow[lane] : NEGV;
      float v1 = (lane + 64 < t) ? grow[lane + 64] : NEGV;
      int bt = b * TST + t;
      for (int k = 0; k < RKK; ++k) {
        float bv = v0; int bi = lane;
        if (v1 > bv) { bv = v1; bi = lane + 64; }
        for (int off = 32; off > 0; off >>= 1) {
          float ov = __shfl_down(bv, off);
          int oi = __shfl_down(bi, off);
          if (ov > bv || (ov == bv && oi < bi)) { bv = ov; bi = oi; }
        }
        bv = __shfl(bv, 0); bi = __shfl(bi, 0);
        if (lane == 0) {
          tix[bt * RKK + k] = bi;
          tmsk[bt * RKK + k] = (bv > NEGV * 0.5f) ? 1 : 0;
        }
        if (bi == lane) v0 = -__builtin_inff();
        if (bi == lane + 64) v1 = -__builtin_inff();
      }
    }
  } else {
    // KQ0 + vqc0 + kb0 + cid
    __shared__ float s_tmp[2][8][DD];
    __shared__ float sU[DD], sWqc[DD], sW2[DD];
    if (tid < 128) {
      sU[tid] = ws[OFF_U + tid];
      sWqc[tid] = Ww[128 + tid];
      sW2[tid] = ws[OFF_W2 + tid];
    }
    {
      int* cid = (int*)(ws + OFF_CID);
      for (int o = tid; o < 127 * 5; o += 256) {
        int tp = 1 + o / 5, k = o - (o / 5) * 5;
        int qn = sq[tp];
        cid[(b * 128 + tp) * 5 + k] = (k == 0) ? qn : qctab[qn * NQCC + k - 1];
      }
    }
    __syncthreads();
    const float* MT = ws + OFF_MT;
    unsigned* KQ0 = (unsigned*)ws + OFF_KQ0;
    int i = tid & 127, half = tid >> 7;
    int s0 = half * 64;
    for (int sb = 0; sb < 64; sb += 8) {
      float acc[8];
#pragma unroll
      for (int u = 0; u < 8; ++u) acc[u] = 0.f;
      for (int j = 0; j < DD; ++j) {
        float w = MT[j * DD + i];
#pragma unroll
        for (int u = 0; u < 8; ++u) acc[u] = fmaf(w, sX[s0 + sb + u][j], acc[u]);
      }
      __syncthreads();
#pragma unroll
      for (int u = 0; u < 8; ++u) s_tmp[half][u][i] = acc[u] + sU[i];
      __syncthreads();
      for (int o = tid; o < 16 * 64; o += 256) {
        int rr = o >> 6, e = o & 63;
        int hh = rr >> 3, uu = rr & 7;
        int s = hh * 64 + sb + uu;
        KQ0[((size_t)b * 128 + s) * 64 + e] = pkh(s_tmp[hh][uu][2 * e], s_tmp[hh][uu][2 * e + 1]);
      }
      __syncthreads();
    }
    if (tid < 128) {
      float a = 0.f, kb = 0.f;
      for (int j = 0; j < DD; ++j) {
        float xv = sX[tid][j];
        a = fmaf(xv, sWqc[j], a);
        kb = fmaf(xv, sW2[j], kb);
      }
      ws[OFF_VQC0 + b * 128 + tid] = a;
      ws[OFF_KB0 + b * 128 + tid] = kb + ws[OFF_C0];
    }
  }
}

// ---------------- K3: batched aggregation + gi1 ----------------
__global__ __launch_bounds__(128) void k_agg(
    const int* __restrict__ qseq, const int* __restrict__ rseq,
    const int* __restrict__ mseq, const int* __restrict__ qnbr,
    const float* __restrict__ Eq, const float* __restrict__ b_agg,
    const float* __restrict__ b_agg_last, const float* __restrict__ b_ih1,
    float* __restrict__ ws) {
  int blk = blockIdx.x;
  int b = blk >> 4, g = blk & 15;
  int t0 = g * 8;
  int nu = (t0 + 8 <= TST) ? 8 : (TST - t0);
  int tid = threadIdx.x;
  __shared__ float s_a[8][DD], s_b[8][DD], s_c[8][DD];
  __shared__ int s_q[8], s_r[8], s_m[8];
  __shared__ int s_n1[8][QNN];
  if (tid < 8) {
    int ok = tid < nu;
    int idx = b * SEQL + (ok ? (t0 + tid) : 0);
    s_q[tid] = qseq[idx];
    s_r[tid] = ok ? rseq[idx] : 0;
    s_m[tid] = ok ? mseq[idx] : 0;
  }
  __syncthreads();
  if (tid < 32) { int u = tid >> 2, k = tid & 3; s_n1[u][k] = qnbr[s_q[u] * QNN + k]; }
  for (int o = tid; o < 8 * 32; o += 128) {
    int u = o >> 5, p = o & 31;
    float4 v = ((const float4*)(Eq + (size_t)s_q[u] * DD))[p];
    s_a[u][p * 4] = v.x; s_a[u][p * 4 + 1] = v.y; s_a[u][p * 4 + 2] = v.z; s_a[u][p * 4 + 3] = v.w;
  }
  __syncthreads();
  const float* WtA0 = ws + OFF_WTA0;
  const float* WtAL = ws + OFF_WTAL;
  const float* WtIH1A = ws + OFF_WTIH1A;
  const float* EcA0 = ws + OFF_ECA0;
  const float* E1C = ws + OFF_E1C;
  float acc[8];
#pragma unroll
  for (int u = 0; u < 8; ++u) acc[u] = 0.f;
  for (int j = 0; j < DD; ++j) {
    float w = WtA0[j * DD + tid];
#pragma unroll
    for (int u = 0; u < 8; ++u) acc[u] = fmaf(w, s_a[u][j], acc[u]);
  }
  float bat = b_agg[tid];
#pragma unroll
  for (int u = 0; u < 8; ++u) {
    int n0 = s_n1[u][0], n1 = s_n1[u][1], n2 = s_n1[u][2], n3 = s_n1[u][3];
    float pre0 = 0.25f * (EcA0[n0 * DD + tid] + EcA0[n1 * DD + tid] + EcA0[n2 * DD + tid] + EcA0[n3 * DD + tid]);
    float e0 = ftanh(acc[u] + pre0 + bat);
    float e1m = 0.25f * (E1C[n0 * DD + tid] + E1C[n1 * DD + tid] + E1C[n2 * DD + tid] + E1C[n3 * DD + tid]);
    s_b[u][tid] = e1m + e0;
  }
  __syncthreads();
#pragma unroll
  for (int u = 0; u < 8; ++u) acc[u] = 0.f;
  for (int j = 0; j < DD; ++j) {
    float w = WtA0[j * DD + tid];
#pragma unroll
    for (int u = 0; u < 8; ++u) acc[u] = fmaf(w, s_b[u][j], acc[u]);
  }
#pragma unroll
  for (int u = 0; u < 8; ++u) s_c[u][tid] = ftanh(acc[u] + bat);
  __syncthreads();
#pragma unroll
  for (int u = 0; u < 8; ++u) acc[u] = 0.f;
  for (int j = 0; j < DD; ++j) {
    float w = WtAL[j * DD + tid];
#pragma unroll
    for (int u = 0; u < 8; ++u) acc[u] = fmaf(w, s_c[u][j], acc[u]);
  }
  float balt = b_agg_last[tid];
#pragma unroll
  for (int u = 0; u < 8; ++u) {
    float aggv = ftanh(acc[u] + balt);
    s_b[u][tid] = s_m[u] ? aggv : s_a[u][tid];
  }
  __syncthreads();
  float g0[8], g1[8], g2[8];
#pragma unroll
  for (int u = 0; u < 8; ++u) { g0[u] = 0.f; g1[u] = 0.f; g2[u] = 0.f; }
  for (int j = 0; j < DD; ++j) {
    float w0 = WtIH1A[j * 384 + tid];
    float w1 = WtIH1A[j * 384 + 128 + tid];
    float w2 = WtIH1A[j * 384 + 256 + tid];
#pragma unroll
    for (int u = 0; u < 8; ++u) {
      float x = s_b[u][j];
      g0[u] = fmaf(w0, x, g0[u]);
      g1[u] = fmaf(w1, x, g1[u]);
      g2[u] = fmaf(w2, x, g2[u]);
    }
  }
  for (int u = 0; u < nu; ++u) {
    const float* ErI = ws + OFF_ERIH1 + s_r[u] * 384;
    float* gi1 = ws + OFF_GI1 + (size_t)(b * TST + t0 + u) * 384;
    gi1[tid] = g0[u] + ErI[tid] + b_ih1[tid];
    gi1[128 + tid] = g1[u] + ErI[128 + tid] + b_ih1[128 + tid];
    gi1[256 + tid] = g2[u] + ErI[256 + tid] + b_ih1[256 + tid];
  }
}

// ---------------- K4: scan; packed-f16 x operands, 2 barriers/step ----------------
__global__ __launch_bounds__(512, 2) void k_seq(
    const float* __restrict__ b_hh1, const float* __restrict__ b_ih2,
    const float* __restrict__ b_hh2, const float* __restrict__ Ww,
    const float* __restrict__ bw, const float* __restrict__ h1i,
    const float* __restrict__ h2i, float* __restrict__ ws,
    float* __restrict__ out) {
  const int tid = threadIdx.x;
  const int b = blockIdx.x;
  const int i = tid >> 2, jc = tid & 3;
  const int lane = tid & 63, wv = tid >> 6;
  const int bt0 = b * TST;

  const float4* gi1f4 = (const float4*)(ws + OFF_GI1);
  const unsigned* KQ0 = (const unsigned*)ws + OFF_KQ0;
  const unsigned* KQC = (const unsigned*)ws + OFF_KQC;
  const float* vqc0_all = ws + OFF_VQC0;
  const float* vqcC_all = ws + OFF_VQCC;
  const float* kb0_all = ws + OFF_KB0;
  const float* kbC_all = ws + OFF_KBC;
  const int* tix_all = (const int*)(ws + OFF_TIX);
  const int* tmsk_all = (const int*)(ws + OFF_TMSK);
  const int* cid_all = (const int*)(ws + OFF_CID);
  const uint4* wp = (const uint4*)((const unsigned*)ws + OFF_WPACK);

  __shared__ float s_h1f[2][144], s_g2f[2][144], s_h2f[144];
  __shared__ unsigned s_h1pk[2][80], s_g2pk[2][80], s_h2pk[80];
  __shared__ unsigned qph_pk[SEQL * 66];
  __shared__ unsigned s_Kq[2][5 * 66];
  __shared__ float s_gi1[384];
  __shared__ float s_vhh[SEQL];
  __shared__ float s_logit[64];
  __shared__ float s_bhh1[384], s_bih2[384], s_bhh2[384];
  __shared__ float s_vh[11], s_vqc[2][5], s_kb[2][5], s_bw;
  __shared__ int s_tix[RKK], s_hm[11], s_cidn[5];

  uint4 wgt[9][4];
#pragma unroll
  for (int c = 0; c < 9; ++c)
#pragma unroll
    for (int kk = 0; kk < 4; ++kk)
      wgt[c][kk] = wp[((c * 4 + jc) * 4 + kk) * 128 + i];
#pragma unroll
  for (int c = 0; c < 9; ++c)
#pragma unroll
    for (int kk = 0; kk < 4; ++kk)
      asm volatile("" : "+v"(wgt[c][kk].x), "+v"(wgt[c][kk].y),
                        "+v"(wgt[c][kk].z), "+v"(wgt[c][kk].w));

  if (tid < 384) { s_bhh1[tid] = b_hh1[tid]; s_bih2[tid] = b_ih2[tid]; s_bhh2[tid] = b_hh2[tid]; }
  if (tid < 128) {
    float h1v = h1i[b * DD + tid], h2v = h2i[b * DD + tid];
    s_h1f[0][XI(tid)] = h1v;
    ((__fp16*)s_h1pk[0])[PH(tid)] = (__fp16)h1v;
    s_h2f[XI(tid)] = h2v;
    ((__fp16*)s_h2pk)[PH(tid)] = (__fp16)h2v;
    s_vhh[tid] = 0.f;
  }
  if (tid >= 55 && tid < 64) s_logit[tid] = NEGV;
  float wh_lo = 0.f, wh_hi = 0.f;
  if (wv == 7) { wh_lo = Ww[lane]; wh_hi = Ww[64 + lane]; }
  if (tid == 0) { s_bw = bw[0]; out[b * SEQL + 1] = 0.f; s_hm[0] = 1; }
  if (tid >= 296 && tid < 301) s_cidn[tid - 296] = cid_all[(b * 128 + 1) * 5 + tid - 296];
  __syncthreads();
  for (int o = tid; o < SEQL * 66; o += 512) qph_pk[o] = 0u;
  if (tid < 96) ((float4*)s_gi1)[tid] = gi1f4[(size_t)bt0 * 96 + tid];
  __syncthreads();

  for (int t = 0; t <= TST; ++t) {
    const int par = t & 1, parn = par ^ 1;
    float4 pf4 = {0.f, 0.f, 0.f, 0.f};
    unsigned pfu = 0, pfu2 = 0; int pfs = 0; float pfv = 0.f, pfkb = 0.f;

    // ==== Phase 1: prefetch(t) + GRU1(t) + logits(t-1)/vh(t-1) ====
    if (t < TST) {
      const int tg = (t + 1 < TST) ? t + 1 : TST - 1;
      if (tid < 96) pf4 = gi1f4[(size_t)(bt0 + tg) * 96 + tid];
      else if (tid < 256) {
        int kx = tid - 96;
        { int s = kx >> 6, e = kx & 63;
          pfu = (s == 0) ? KQ0[(size_t)(b * 128 + t + 1) * 64 + e] : KQC[s_cidn[s] * 64 + e]; }
        { int kx2 = kx + 160; int s = kx2 >> 6, e = kx2 & 63;
          pfu2 = KQC[s_cidn[s] * 64 + e]; }
      } else if (tid < 291) {
        int k = tid - 256;
        if (k < 5) pfv = (k == 0) ? vqc0_all[b * 128 + t + 1] : vqcC_all[s_cidn[k]];
        else if (k < 10) { int s = k - 5; pfkb = (s == 0) ? kb0_all[b * 128 + t + 1] : kbC_all[s_cidn[s]]; }
        else if (k < 20) pfs = tix_all[(bt0 + t) * RKK + k - 10];
        else if (k < 30) pfs = tmsk_all[(bt0 + t) * RKK + k - 20];
        else { int tn = (t + 1 < TST) ? t + 1 : TST - 1; pfs = cid_all[(b * 128 + tn + 1) * 5 + k - 30]; }
      }
      const uint4* xp = (const uint4*)s_h1pk[par] + jc * 5;
      float a0 = 0.f, a1 = 0.f, a2 = 0.f;
#pragma unroll
      for (int kk = 0; kk < 4; ++kk) {
        uint4 xk = xp[kk];
        uint4 w;
        w = wgt[0][kk]; a0 = fd2u(a0, w.x, xk.x); a0 = fd2u(a0, w.y, xk.y); a0 = fd2u(a0, w.z, xk.z); a0 = fd2u(a0, w.w, xk.w);
        w = wgt[1][kk]; a1 = fd2u(a1, w.x, xk.x); a1 = fd2u(a1, w.y, xk.y); a1 = fd2u(a1, w.z, xk.z); a1 = fd2u(a1, w.w, xk.w);
        w = wgt[2][kk]; a2 = fd2u(a2, w.x, xk.x); a2 = fd2u(a2, w.y, xk.y); a2 = fd2u(a2, w.z, xk.z); a2 = fd2u(a2, w.w, xk.w);
      }
      a0 += __shfl_down(a0, 2); a0 += __shfl_down(a0, 1);
      a1 += __shfl_down(a1, 2); a1 += __shfl_down(a1, 1);
      a2 += __shfl_down(a2, 2); a2 += __shfl_down(a2, 1);
      if (jc == 0) {
        float r = sigm(s_gi1[i] + a0 + s_bhh1[i]);
        float z = sigm(s_gi1[128 + i] + a1 + s_bhh1[128 + i]);
        float n = ftanh(s_gi1[256 + i] + r * (a2 + s_bhh1[256 + i]));
        float h1n = (1.f - z) * n + z * s_h1f[par][XI(i)];
        s_h1f[parn][XI(i)] = h1n;
        ((__fp16*)s_h1pk[parn])[PH(i)] = (__fp16)h1n;
      }
    }
    if (t >= 1) {
      if (tid < 440) {
        int p = tid >> 3, sub = tid & 7;
        int q = p / 5, s = p - q * 5;
        const unsigned* kpr = &s_Kq[parn][s * 66 + sub * 8];
        float a = 0.f;
        if (q == 0) {
          const unsigned* g2u = s_g2pk[parn];
          int e0 = sub * 16;
#pragma unroll
          for (int k = 0; k < 8; ++k) a = fd2u(a, kpr[k], g2u[PU(e0 + 2 * k)]);
        } else {
          const unsigned* ro = qph_pk + s_tix[q - 1] * 66;
#pragma unroll
          for (int k = 0; k < 8; ++k) a = fd2u(a, ro[sub * 8 + k], kpr[k]);
        }
        a += __shfl_down(a, 4);
        a += __shfl_down(a, 2);
        a += __shfl_down(a, 1);
        if (sub == 0) s_logit[p] = s_hm[q] ? (a + s_kb[parn][s]) : NEGV;
      } else if (wv == 7) {
        float pa = s_g2f[parn][XI(lane)] * wh_lo + s_g2f[parn][XI(64 + lane)] * wh_hi;
        for (int off = 32; off > 0; off >>= 1) pa += __shfl_down(pa, off);
        if (lane == 0) s_vh[0] = pa;
        if (lane >= 16 && lane < 26) s_vh[1 + lane - 16] = s_vhh[s_tix[lane - 16]];
      }
    }
    bar();

    // ==== Phase 2: GRU2(t) + softmax/out(t-1) + commits ====
    if (t < TST) {
      const uint4* xn = (const uint4*)s_h1pk[parn] + jc * 5;
      const uint4* xh = (t <= 1) ? ((const uint4*)s_h2pk + jc * 5)
                                 : ((const uint4*)s_g2pk[parn] + jc * 5);
      float a0 = 0.f, a1 = 0.f, a2 = 0.f, c0 = 0.f, c1 = 0.f, c2 = 0.f;
#pragma unroll
      for (int kk = 0; kk < 4; ++kk) {
        uint4 xa = xn[kk], xb = xh[kk];
        uint4 w;
        w = wgt[3][kk]; a0 = fd2u(a0, w.x, xa.x); a0 = fd2u(a0, w.y, xa.y); a0 = fd2u(a0, w.z, xa.z); a0 = fd2u(a0, w.w, xa.w);
        w = wgt[4][kk]; a1 = fd2u(a1, w.x, xa.x); a1 = fd2u(a1, w.y, xa.y); a1 = fd2u(a1, w.z, xa.z); a1 = fd2u(a1, w.w, xa.w);
        w = wgt[5][kk]; a2 = fd2u(a2, w.x, xa.x); a2 = fd2u(a2, w.y, xa.y); a2 = fd2u(a2, w.z, xa.z); a2 = fd2u(a2, w.w, xa.w);
        w = wgt[6][kk]; c0 = fd2u(c0, w.x, xb.x); c0 = fd2u(c0, w.y, xb.y); c0 = fd2u(c0, w.z, xb.z); c0 = fd2u(c0, w.w, xb.w);
        w = wgt[7][kk]; c1 = fd2u(c1, w.x, xb.x); c1 = fd2u(c1, w.y, xb.y); c1 = fd2u(c1, w.z, xb.z); c1 = fd2u(c1, w.w, xb.w);
        w = wgt[8][kk]; c2 = fd2u(c2, w.x, xb.x); c2 = fd2u(c2, w.y, xb.y); c2 = fd2u(c2, w.z, xb.z); c2 = fd2u(c2, w.w, xb.w);
      }
      a0 += __shfl_down(a0, 2); a0 += __shfl_down(a0, 1);
      a1 += __shfl_down(a1, 2); a1 += __shfl_down(a1, 1);
      a2 += __shfl_down(a2, 2); a2 += __shfl_down(a2, 1);
      c0 += __shfl_down(c0, 2); c0 += __shfl_down(c0, 1);
      c1 += __shfl_down(c1, 2); c1 += __shfl_down(c1, 1);
      c2 += __shfl_down(c2, 2); c2 += __shfl_down(c2, 1);
      if (jc == 0) {
        float r = sigm(a0 + s_bih2[i] + c0 + s_bhh2[i]);
        float z = sigm(a1 + s_bih2[128 + i] + c1 + s_bhh2[128 + i]);
        float n = ftanh(a2 + s_bih2[256 + i] + r * (c2 + s_bhh2[256 + i]));
        float h2old = (t <= 1) ? s_h2f[XI(i)] : s_g2f[parn][XI(i)];
        float g2v = (1.f - z) * n + z * h2old;
        s_g2f[par][XI(i)] = g2v;
        ((__fp16*)s_g2pk[par])[PH(i)] = (__fp16)g2v;
      }
    }
    if (t >= 1 && wv == 7) {
      float l = s_logit[lane];
      float m = l;
      for (int off = 32; off > 0; off >>= 1) m = fmaxf(m, __shfl_xor(m, off));
      float e = __expf(l - m);
      float v = 0.f;
      if (lane < 55) {
        int q = lane / 5, s = lane - q * 5;
        v = sigm(s_vh[q] + s_vqc[parn][s] + s_bw);
      }
      float num = e * v, den = e;
      for (int off = 32; off > 0; off >>= 1) { num += __shfl_xor(num, off); den += __shfl_xor(den, off); }
      if (lane == 0) out[b * SEQL + ((t - 1 == 0) ? 0 : t)] = num / den;
    }
    if (t < TST) {
      if (tid < 96) ((float4*)s_gi1)[tid] = pf4;
      else if (tid < 256) {
        int kx = tid - 96;
        { int s = kx >> 6, e = kx & 63; s_Kq[par][s * 66 + e] = pfu; }
        { int kx2 = kx + 160; int s = kx2 >> 6, e = kx2 & 63; s_Kq[par][s * 66 + e] = pfu2; }
      } else if (tid < 291) {
        int k = tid - 256;
        if (k < 5) s_vqc[par][k] = pfv;
        else if (k < 10) s_kb[par][k - 5] = pfkb;
        else if (k < 20) s_tix[k - 10] = pfs;
        else if (k < 30) s_hm[1 + k - 20] = pfs;
        else s_cidn[k - 30] = pfs;
      }
    }
    if (t >= 2 && tid >= 320 && tid < 384) {
      int k2 = tid - 320;
      qph_pk[(t - 1) * 66 + k2] = s_g2pk[parn][PU(2 * k2)];
    }
    if (t >= 2 && tid == 0) s_vhh[t - 1] = s_vh[0];
    bar();
  }
}

extern "C" void kernel_launch(void* const* d_in, const int* in_sizes, int n_in,
                              void* d_out, int out_size, void* d_ws, size_t ws_size,
                              hipStream_t stream) {
  (void)in_sizes; (void)n_in; (void)out_size; (void)ws_size;
  const int* qseq = (const int*)d_in[0];
  const int* rseq = (const int*)d_in[1];
  const int* mseq = (const int*)d_in[2];
  const int* qnbr = (const int*)d_in[3];
  const int* cnbr = (const int*)d_in[4];
  const int* qctab = (const int*)d_in[5];
  const float* Eq = (const float*)d_in[6];
  const float* Ec = (const float*)d_in[7];
  const float* Er = (const float*)d_in[8];
  const float* W_ih1 = (const float*)d_in[9];
  const float* W_hh1 = (const float*)d_in[10];
  const float* b_ih1 = (const float*)d_in[11];
  const float* b_hh1 = (const float*)d_in[12];
  const float* W_ih2 = (const float*)d_in[13];
  const float* W_hh2 = (const float*)d_in[14];
  const float* b_ih2 = (const float*)d_in[15];
  const float* b_hh2 = (const float*)d_in[16];
  const float* W_agg = (const float*)d_in[17];
  const float* b_agg = (const float*)d_in[18];
  const float* W_agg_last = (const float*)d_in[19];
  const float* b_agg_last = (const float*)d_in[20];
  const float* Wq = (const float*)d_in[21];
  const float* bq = (const float*)d_in[22];
  const float* Wk = (const float*)d_in[23];
  const float* bk = (const float*)d_in[24];
  const float* Ww = (const float*)d_in[25];
  const float* bw = (const float*)d_in[26];
  const float* h1i = (const float*)d_in[27];
  const float* h2i = (const float*)d_in[28];
  float* ws = (float*)d_ws;
  float* out = (float*)d_out;

  hipLaunchKernelGGL(k_prep, dim3(805), dim3(256), 0, stream,
                     W_hh1, W_ih2, W_hh2, W_agg, W_agg_last, W_ih1, Er,
                     Wq, Wk, bq, bk, ws);
  hipLaunchKernelGGL(k_concept, dim3(1000), dim3(128), 0, stream,
                     cnbr, Eq, Ec, b_agg, Ww, ws);
  hipLaunchKernelGGL(k_gram, dim3(256), dim3(256), 0, stream,
                     qseq, qctab, Eq, Ww, ws);
  hipLaunchKernelGGL(k_agg, dim3(BSZ * 16), dim3(128), 0, stream,
                     qseq, rseq, mseq, qnbr, Eq, b_agg, b_agg_last, b_ih1, ws);
  hipLaunchKernelGGL(k_seq, dim3(BSZ), dim3(512), 0, stream,
                     b_hh1, b_ih2, b_hh2, Ww, bw, h1i, h2i, ws, out);
}

// Round 18
// 573.476 us; speedup vs baseline: 1.1931x; 1.1931x over previous
//
#include <hip/hip_runtime.h>

#define DD 128
#define BSZ 128
#define SEQL 128
#define TST 127
#define QNN 4
#define CNN 10
#define NQCC 4
#define RKK 10
#define NEGV -1000000000.0f

// ---- workspace float offsets ----
#define OFF_WTA0    0
#define OFF_WTA1    16384
#define OFF_WTAL    32768
#define OFF_WTIH1A  49152
#define OFF_ERIH1   98304
#define OFF_MT      99072
#define OFF_WPACK   115456
#define OFF_ECA0    189184
#define OFF_E1C     317184
#define OFF_KQC     445184
#define OFF_VQCC    509184
#define OFF_KBC     510184
#define OFF_U       511184
#define OFF_W2      511312
#define OFF_C0      511440
#define OFF_GRAM    511488
#define OFF_GI1     511488
#define OFF_KQ0     6753792
#define OFF_VQC0    7802368
#define OFF_KB0     7818752
#define OFF_TIX     7835136
#define OFF_TMSK    7997696
#define OFF_CID     8160256

// padded f32 x index: chunk stride 36 floats
#define XI(e) ((e) + (((e) >> 5) << 2))
// packed f16 x: chunk stride 40 halfwords (80B, 16B-aligned)
#define PH(e) ((((e) >> 5) * 40) + ((e) & 31))
#define PU(e) ((((e) >> 5) * 20) + (((e) & 31) >> 1))

typedef __fp16 h2 __attribute__((ext_vector_type(2)));

__device__ __forceinline__ float sigm(float x) { return 1.0f / (1.0f + __expf(-x)); }
// fast tanh: (1-e^{-2|x|})/(1+e^{-2|x|}) with sign; no overflow
__device__ __forceinline__ float ftanh(float x) {
  float ax = fabsf(x);
  float T = __expf(-2.f * ax);
  float r = (1.f - T) * __builtin_amdgcn_rcpf(1.f + T);
  return copysignf(r, x);
}
__device__ __forceinline__ unsigned pkh(float a, float b) {
  h2 v; v.x = (__fp16)a; v.y = (__fp16)b;
  return __builtin_bit_cast(unsigned, v);
}
__device__ __forceinline__ float fd2u(float acc, unsigned w, unsigned x) {
  return __builtin_amdgcn_fdot2(__builtin_bit_cast(h2, w), __builtin_bit_cast(h2, x), acc, false);
}
// raw barrier: LDS drained, global loads stay in flight
__device__ __forceinline__ void bar() {
  asm volatile("s_waitcnt lgkmcnt(0)" ::: "memory");
  __builtin_amdgcn_s_barrier();
  asm volatile("" ::: "memory");
}

// ---------------- K0a: tables + WPACK (blocks 0..674)  |  mqk (blocks 675..804) ----------------
__global__ __launch_bounds__(256) void k_prep(
    const float* __restrict__ W_hh1, const float* __restrict__ W_ih2,
    const float* __restrict__ W_hh2, const float* __restrict__ W_agg,
    const float* __restrict__ W_agg_last, const float* __restrict__ W_ih1,
    const float* __restrict__ Er, const float* __restrict__ Wq,
    const float* __restrict__ Wk, const float* __restrict__ bq,
    const float* __restrict__ bk, float* __restrict__ ws) {
  int tid = threadIdx.x;
  if (blockIdx.x < 675) {
    int idx = blockIdx.x * 256 + tid;
    const int TOT = 172800;
    for (int o = idx; o < TOT; o += 675 * 256) {
      int r = o;
      if (r < 16384) { int j = r >> 7, i = r & 127; ws[OFF_WTA0 + r] = W_agg[i * 128 + j]; continue; }
      r -= 16384;
      if (r < 16384) { int j = r >> 7, i = r & 127; ws[OFF_WTA1 + r] = W_agg[16384 + i * 128 + j]; continue; }
      r -= 16384;
      if (r < 16384) { int j = r >> 7, i = r & 127; ws[OFF_WTAL + r] = W_agg_last[i * 128 + j]; continue; }
      r -= 16384;
      if (r < 49152) { int j = r / 384, i = r % 384; ws[OFF_WTIH1A + r] = W_ih1[i * 256 + j]; continue; }
      r -= 49152;
      if (r < 768) {
        int rr = r / 384, i2 = r % 384;
        float a = 0.f;
        for (int j = 0; j < 128; ++j) a += Er[rr * 128 + j] * W_ih1[i2 * 256 + 128 + j];
        ws[OFF_ERIH1 + r] = a; continue;
      }
      r -= 768;
      {
        int n = r & 3; int q = r >> 2;
        int i = q & 127; q >>= 7;
        int kk = q & 3; q >>= 2;
        int jc = q & 3; int c = q >> 2;
        int j0 = jc * 32 + kk * 8 + n * 2;
        const float* row;
        if (c < 3) row = W_hh1 + (size_t)(c * 128 + i) * 128;
        else if (c < 6) row = W_ih2 + (size_t)((c - 3) * 128 + i) * 128;
        else row = W_hh2 + (size_t)((c - 6) * 128 + i) * 128;
        ((unsigned*)ws)[OFF_WPACK + r] = pkh(row[j0], row[j0 + 1]);
      }
    }
  } else {
    int j = blockIdx.x - 675;
    __shared__ float wkc[128];
    __shared__ float sc[128];
    if (j < 128) {
      if (tid < 128) wkc[tid] = Wk[tid * 128 + j];
      __syncthreads();
      if (tid < 128) {
        float a = 0.f;
        for (int l = 0; l < 128; ++l) a = fmaf(Wq[l * 128 + tid], wkc[l], a);
        ws[OFF_MT + j * 128 + tid] = a;
      }
    } else if (j == 128) {
      if (tid < 128) {
        float a = 0.f;
        for (int l = 0; l < 128; ++l) a = fmaf(Wq[l * 128 + tid], bk[l], a);
        ws[OFF_U + tid] = a;
      }
    } else {
      if (tid < 128) {
        float a = 0.f;
        for (int l = 0; l < 128; ++l) a = fmaf(bq[l], Wk[l * 128 + tid], a);
        ws[OFF_W2 + tid] = a;
        sc[tid] = bq[tid] * bk[tid];
      }
      __syncthreads();
      if (tid == 0) { float s = 0.f; for (int l = 0; l < 128; ++l) s += sc[l]; ws[OFF_C0] = s; }
    }
  }
}

// ---------------- K0b: per-concept tables ----------------
__global__ __launch_bounds__(128) void k_concept(
    const int* __restrict__ cnbr, const float* __restrict__ Eq,
    const float* __restrict__ Ec, const float* __restrict__ b_agg,
    const float* __restrict__ Ww, float* __restrict__ ws) {
  int c = blockIdx.x;
  int tid = threadIdx.x;
  __shared__ int s_nb[CNN];
  __shared__ float s_v[DD], s_ec[DD], s_t2[DD], s_w2[DD], s_kb2[DD];
  if (tid < CNN) s_nb[tid] = cnbr[c * CNN + tid];
  __syncthreads();
  float ec = Ec[c * DD + tid];
  float cm = 0.f;
#pragma unroll
  for (int l = 0; l < CNN; ++l) cm += Eq[(size_t)s_nb[l] * DD + tid];
  s_ec[tid] = ec;
  s_v[tid] = cm * 0.1f + ec;
  __syncthreads();
  const float* WtA0 = ws + OFF_WTA0;
  const float* WtA1 = ws + OFF_WTA1;
  const float* MT = ws + OFF_MT;
  float a1 = 0.f, a0 = 0.f, kq = 0.f;
#pragma unroll 8
  for (int j = 0; j < DD; ++j) {
    a1 += WtA1[j * DD + tid] * s_v[j];
    a0 += WtA0[j * DD + tid] * s_ec[j];
    kq += MT[j * DD + tid] * s_ec[j];
  }
  ws[OFF_E1C + c * DD + tid] = ftanh(a1 + b_agg[DD + tid]);
  ws[OFF_ECA0 + c * DD + tid] = a0;
  s_t2[tid] = kq + ws[OFF_U + tid];
  s_w2[tid] = s_ec[tid] * Ww[128 + tid];
  s_kb2[tid] = s_ec[tid] * ws[OFF_W2 + tid];
  __syncthreads();
  if (tid < 64) {
    ((unsigned*)ws)[OFF_KQC + c * 64 + tid] = pkh(s_t2[2 * tid], s_t2[2 * tid + 1]);
    float pa = s_w2[tid] + s_w2[tid + 64];
    float pb = s_kb2[tid] + s_kb2[tid + 64];
    for (int off = 32; off > 0; off >>= 1) { pa += __shfl_down(pa, off); pb += __shfl_down(pb, off); }
    if (tid == 0) { ws[OFF_VQCC + c] = pa; ws[OFF_KBC + c] = pb + ws[OFF_C0]; }
  }
}

// ---------------- K1: blocks 0..127 Gram(b) ; blocks 128..255 KQ0/vqc0/kb0(b-128) ----------------
__global__ __launch_bounds__(256) void k_gram(
    const int* __restrict__ qseq, const float* __restrict__ Eq,
    const float* __restrict__ Ww, float* __restrict__ ws) {
  int role = blockIdx.x >> 7;
  int b = blockIdx.x & 127;
  int tid = threadIdx.x;
  __shared__ float sX[128][129];
  __shared__ int sq[SEQL];
  if (tid < 128) sq[tid] = qseq[b * SEQL + tid];
  __syncthreads();
  for (int o = tid; o < 128 * 32; o += 256) {
    int s = o >> 5, p = o & 31;
    float4 v = ((const float4*)(Eq + (size_t)sq[s] * DD))[p];
    sX[s][p * 4] = v.x; sX[s][p * 4 + 1] = v.y; sX[s][p * 4 + 2] = v.z; sX[s][p * 4 + 3] = v.w;
  }
  __syncthreads();
  if (role == 0) {
    // Gram
    int r0 = (tid >> 4) * 8, c0 = (tid & 15) * 8;
    float acc[8][8];
#pragma unroll
    for (int u = 0; u < 8; ++u)
#pragma unroll
      for (int v = 0; v < 8; ++v) acc[u][v] = 0.f;
    for (int k = 0; k < 128; ++k) {
      float a[8], bb[8];
#pragma unroll
      for (int u = 0; u < 8; ++u) { a[u] = sX[r0 + u][k]; bb[u] = sX[c0 + u][k]; }
#pragma unroll
      for (int u = 0; u < 8; ++u)
#pragma unroll
        for (int v = 0; v < 8; ++v) acc[u][v] = fmaf(a[u], bb[v], acc[u][v]);
    }
    float* gb = ws + OFF_GRAM + (size_t)b * 16384;
#pragma unroll
    for (int u = 0; u < 8; ++u) {
      float4 v0 = {acc[u][0], acc[u][1], acc[u][2], acc[u][3]};
      float4 v1 = {acc[u][4], acc[u][5], acc[u][6], acc[u][7]};
      ((float4*)(gb + (size_t)(r0 + u) * 128 + c0))[0] = v0;
      ((float4*)(gb + (size_t)(r0 + u) * 128 + c0 + 4))[0] = v1;
    }
  } else {
    // KQ0 + vqc0 + kb0
    __shared__ float s_tmp[2][8][DD];
    __shared__ float sU[DD], sWqc[DD], sW2[DD];
    if (tid < 128) {
      sU[tid] = ws[OFF_U + tid];
      sWqc[tid] = Ww[128 + tid];
      sW2[tid] = ws[OFF_W2 + tid];
    }
    __syncthreads();
    const float* MT = ws + OFF_MT;
    unsigned* KQ0 = (unsigned*)ws + OFF_KQ0;
    int i = tid & 127, half = tid >> 7;
    int s0 = half * 64;
    for (int sb = 0; sb < 64; sb += 8) {
      float acc[8];
#pragma unroll
      for (int u = 0; u < 8; ++u) acc[u] = 0.f;
      for (int j = 0; j < DD; ++j) {
        float w = MT[j * DD + i];
#pragma unroll
        for (int u = 0; u < 8; ++u) acc[u] = fmaf(w, sX[s0 + sb + u][j], acc[u]);
      }
      __syncthreads();
#pragma unroll
      for (int u = 0; u < 8; ++u) s_tmp[half][u][i] = acc[u] + sU[i];
      __syncthreads();
      for (int o = tid; o < 16 * 64; o += 256) {
        int rr = o >> 6, e = o & 63;
        int hh = rr >> 3, uu = rr & 7;
        int s = hh * 64 + sb + uu;
        KQ0[((size_t)b * 128 + s) * 64 + e] = pkh(s_tmp[hh][uu][2 * e], s_tmp[hh][uu][2 * e + 1]);
      }
      __syncthreads();
    }
    if (tid < 128) {
      float a = 0.f, kb = 0.f;
      for (int j = 0; j < DD; ++j) {
        float xv = sX[tid][j];
        a = fmaf(xv, sWqc[j], a);
        kb = fmaf(xv, sW2[j], kb);
      }
      ws[OFF_VQC0 + b * 128 + tid] = a;
      ws[OFF_KB0 + b * 128 + tid] = kb + ws[OFF_C0];
    }
  }
}

// ---------------- K2: top-10 from gram row, one t per WAVE ----------------
__global__ __launch_bounds__(128) void k_topk(
    const int* __restrict__ qseq, const int* __restrict__ qctab,
    float* __restrict__ ws) {
  int* tix = (int*)(ws + OFF_TIX);
  int* tmsk = (int*)(ws + OFF_TMSK);
  int* cid = (int*)(ws + OFF_CID);
  int tid = threadIdx.x;
  int lane = tid & 63, wv = tid >> 6;
  int bt = blockIdx.x * 2 + wv;
  int b = bt / TST, t = bt - b * TST;
  if (lane < 5) {
    int qn = qseq[b * SEQL + t + 1];
    cid[(b * 128 + t + 1) * 5 + lane] = (lane == 0) ? qn : qctab[qn * NQCC + lane - 1];
  }
  const float* grow = ws + OFF_GRAM + ((size_t)b * 128 + (t + 1)) * 128;
  float v0 = (lane < t) ? grow[lane] : NEGV;
  float v1 = (lane + 64 < t) ? grow[lane + 64] : NEGV;
  for (int k = 0; k < RKK; ++k) {
    float bv = v0; int bi = lane;
    if (v1 > bv) { bv = v1; bi = lane + 64; }
    for (int off = 32; off > 0; off >>= 1) {
      float ov = __shfl_down(bv, off);
      int oi = __shfl_down(bi, off);
      if (ov > bv || (ov == bv && oi < bi)) { bv = ov; bi = oi; }
    }
    bv = __shfl(bv, 0); bi = __shfl(bi, 0);
    if (lane == 0) {
      tix[bt * RKK + k] = bi;
      tmsk[bt * RKK + k] = (bv > NEGV * 0.5f) ? 1 : 0;
    }
    if (bi == lane) v0 = -__builtin_inff();
    if (bi == lane + 64) v1 = -__builtin_inff();
  }
}

// ---------------- K3: batched aggregation + gi1 ----------------
__global__ __launch_bounds__(128) void k_agg(
    const int* __restrict__ qseq, const int* __restrict__ rseq,
    const int* __restrict__ mseq, const int* __restrict__ qnbr,
    const float* __restrict__ Eq, const float* __restrict__ b_agg,
    const float* __restrict__ b_agg_last, const float* __restrict__ b_ih1,
    float* __restrict__ ws) {
  int blk = blockIdx.x;
  int b = blk >> 4, g = blk & 15;
  int t0 = g * 8;
  int nu = (t0 + 8 <= TST) ? 8 : (TST - t0);
  int tid = threadIdx.x;
  __shared__ float s_a[8][DD], s_b[8][DD], s_c[8][DD];
  __shared__ int s_q[8], s_r[8], s_m[8];
  __shared__ int s_n1[8][QNN];
  if (tid < 8) {
    int ok = tid < nu;
    int idx = b * SEQL + (ok ? (t0 + tid) : 0);
    s_q[tid] = qseq[idx];
    s_r[tid] = ok ? rseq[idx] : 0;
    s_m[tid] = ok ? mseq[idx] : 0;
  }
  __syncthreads();
  if (tid < 32) { int u = tid >> 2, k = tid & 3; s_n1[u][k] = qnbr[s_q[u] * QNN + k]; }
  for (int o = tid; o < 8 * 32; o += 128) {
    int u = o >> 5, p = o & 31;
    float4 v = ((const float4*)(Eq + (size_t)s_q[u] * DD))[p];
    s_a[u][p * 4] = v.x; s_a[u][p * 4 + 1] = v.y; s_a[u][p * 4 + 2] = v.z; s_a[u][p * 4 + 3] = v.w;
  }
  __syncthreads();
  const float* WtA0 = ws + OFF_WTA0;
  const float* WtAL = ws + OFF_WTAL;
  const float* WtIH1A = ws + OFF_WTIH1A;
  const float* EcA0 = ws + OFF_ECA0;
  const float* E1C = ws + OFF_E1C;
  float acc[8];
#pragma unroll
  for (int u = 0; u < 8; ++u) acc[u] = 0.f;
  for (int j = 0; j < DD; ++j) {
    float w = WtA0[j * DD + tid];
#pragma unroll
    for (int u = 0; u < 8; ++u) acc[u] = fmaf(w, s_a[u][j], acc[u]);
  }
  float bat = b_agg[tid];
#pragma unroll
  for (int u = 0; u < 8; ++u) {
    int n0 = s_n1[u][0], n1 = s_n1[u][1], n2 = s_n1[u][2], n3 = s_n1[u][3];
    float pre0 = 0.25f * (EcA0[n0 * DD + tid] + EcA0[n1 * DD + tid] + EcA0[n2 * DD + tid] + EcA0[n3 * DD + tid]);
    float e0 = ftanh(acc[u] + pre0 + bat);
    float e1m = 0.25f * (E1C[n0 * DD + tid] + E1C[n1 * DD + tid] + E1C[n2 * DD + tid] + E1C[n3 * DD + tid]);
    s_b[u][tid] = e1m + e0;
  }
  __syncthreads();
#pragma unroll
  for (int u = 0; u < 8; ++u) acc[u] = 0.f;
  for (int j = 0; j < DD; ++j) {
    float w = WtA0[j * DD + tid];
#pragma unroll
    for (int u = 0; u < 8; ++u) acc[u] = fmaf(w, s_b[u][j], acc[u]);
  }
#pragma unroll
  for (int u = 0; u < 8; ++u) s_c[u][tid] = ftanh(acc[u] + bat);
  __syncthreads();
#pragma unroll
  for (int u = 0; u < 8; ++u) acc[u] = 0.f;
  for (int j = 0; j < DD; ++j) {
    float w = WtAL[j * DD + tid];
#pragma unroll
    for (int u = 0; u < 8; ++u) acc[u] = fmaf(w, s_c[u][j], acc[u]);
  }
  float balt = b_agg_last[tid];
#pragma unroll
  for (int u = 0; u < 8; ++u) {
    float aggv = ftanh(acc[u] + balt);
    s_b[u][tid] = s_m[u] ? aggv : s_a[u][tid];
  }
  __syncthreads();
  float g0[8], g1[8], g2[8];
#pragma unroll
  for (int u = 0; u < 8; ++u) { g0[u] = 0.f; g1[u] = 0.f; g2[u] = 0.f; }
  for (int j = 0; j < DD; ++j) {
    float w0 = WtIH1A[j * 384 + tid];
    float w1 = WtIH1A[j * 384 + 128 + tid];
    float w2 = WtIH1A[j * 384 + 256 + tid];
#pragma unroll
    for (int u = 0; u < 8; ++u) {
      float x = s_b[u][j];
      g0[u] = fmaf(w0, x, g0[u]);
      g1[u] = fmaf(w1, x, g1[u]);
      g2[u] = fmaf(w2, x, g2[u]);
    }
  }
  for (int u = 0; u < nu; ++u) {
    const float* ErI = ws + OFF_ERIH1 + s_r[u] * 384;
    float* gi1 = ws + OFF_GI1 + (size_t)(b * TST + t0 + u) * 384;
    gi1[tid] = g0[u] + ErI[tid] + b_ih1[tid];
    gi1[128 + tid] = g1[u] + ErI[128 + tid] + b_ih1[128 + tid];
    gi1[256 + tid] = g2[u] + ErI[256 + tid] + b_ih1[256 + tid];
  }
}

// ---------------- K4: scan; packed-f16 x operands, 2 barriers/step ----------------
__global__ __launch_bounds__(512, 2) void k_seq(
    const float* __restrict__ b_hh1, const float* __restrict__ b_ih2,
    const float* __restrict__ b_hh2, const float* __restrict__ Ww,
    const float* __restrict__ bw, const float* __restrict__ h1i,
    const float* __restrict__ h2i, float* __restrict__ ws,
    float* __restrict__ out) {
  const int tid = threadIdx.x;
  const int b = blockIdx.x;
  const int i = tid >> 2, jc = tid & 3;
  const int lane = tid & 63, wv = tid >> 6;
  const int bt0 = b * TST;

  const float4* gi1f4 = (const float4*)(ws + OFF_GI1);
  const unsigned* KQ0 = (const unsigned*)ws + OFF_KQ0;
  const unsigned* KQC = (const unsigned*)ws + OFF_KQC;
  const float* vqc0_all = ws + OFF_VQC0;
  const float* vqcC_all = ws + OFF_VQCC;
  const float* kb0_all = ws + OFF_KB0;
  const float* kbC_all = ws + OFF_KBC;
  const int* tix_all = (const int*)(ws + OFF_TIX);
  const int* tmsk_all = (const int*)(ws + OFF_TMSK);
  const int* cid_all = (const int*)(ws + OFF_CID);
  const uint4* wp = (const uint4*)((const unsigned*)ws + OFF_WPACK);

  __shared__ float s_h1f[2][144], s_g2f[2][144], s_h2f[144];
  __shared__ unsigned s_h1pk[2][80], s_g2pk[2][80], s_h2pk[80];
  __shared__ unsigned qph_pk[SEQL * 66];
  __shared__ unsigned s_Kq[2][5 * 66];
  __shared__ float s_gi1[384];
  __shared__ float s_vhh[SEQL];
  __shared__ float s_logit[64];
  __shared__ float s_bhh1[384], s_bih2[384], s_bhh2[384];
  __shared__ float s_vh[11], s_vqc[2][5], s_kb[2][5], s_bw;
  __shared__ int s_tix[RKK], s_hm[11], s_cidn[5];

  uint4 wgt[9][4];
#pragma unroll
  for (int c = 0; c < 9; ++c)
#pragma unroll
    for (int kk = 0; kk < 4; ++kk)
      wgt[c][kk] = wp[((c * 4 + jc) * 4 + kk) * 128 + i];
#pragma unroll
  for (int c = 0; c < 9; ++c)
#pragma unroll
    for (int kk = 0; kk < 4; ++kk)
      asm volatile("" : "+v"(wgt[c][kk].x), "+v"(wgt[c][kk].y),
                        "+v"(wgt[c][kk].z), "+v"(wgt[c][kk].w));

  if (tid < 384) { s_bhh1[tid] = b_hh1[tid]; s_bih2[tid] = b_ih2[tid]; s_bhh2[tid] = b_hh2[tid]; }
  if (tid < 128) {
    float h1v = h1i[b * DD + tid], h2v = h2i[b * DD + tid];
    s_h1f[0][XI(tid)] = h1v;
    ((__fp16*)s_h1pk[0])[PH(tid)] = (__fp16)h1v;
    s_h2f[XI(tid)] = h2v;
    ((__fp16*)s_h2pk)[PH(tid)] = (__fp16)h2v;
    s_vhh[tid] = 0.f;
  }
  if (tid >= 55 && tid < 64) s_logit[tid] = NEGV;
  float wh_lo = 0.f, wh_hi = 0.f;
  if (wv == 7) { wh_lo = Ww[lane]; wh_hi = Ww[64 + lane]; }
  if (tid == 0) { s_bw = bw[0]; out[b * SEQL + 1] = 0.f; s_hm[0] = 1; }
  if (tid >= 296 && tid < 301) s_cidn[tid - 296] = cid_all[(b * 128 + 1) * 5 + tid - 296];
  __syncthreads();
  for (int o = tid; o < SEQL * 66; o += 512) qph_pk[o] = 0u;
  if (tid < 96) ((float4*)s_gi1)[tid] = gi1f4[(size_t)bt0 * 96 + tid];
  __syncthreads();

  for (int t = 0; t <= TST; ++t) {
    const int par = t & 1, parn = par ^ 1;
    float4 pf4 = {0.f, 0.f, 0.f, 0.f};
    unsigned pfu = 0, pfu2 = 0; int pfs = 0; float pfv = 0.f, pfkb = 0.f;

    // ==== Phase 1: prefetch(t) + GRU1(t) + logits(t-1)/vh(t-1) ====
    if (t < TST) {
      const int tg = (t + 1 < TST) ? t + 1 : TST - 1;
      if (tid < 96) pf4 = gi1f4[(size_t)(bt0 + tg) * 96 + tid];
      else if (tid < 256) {
        int kx = tid - 96;
        { int s = kx >> 6, e = kx & 63;
          pfu = (s == 0) ? KQ0[(size_t)(b * 128 + t + 1) * 64 + e] : KQC[s_cidn[s] * 64 + e]; }
        { int kx2 = kx + 160; int s = kx2 >> 6, e = kx2 & 63;
          pfu2 = KQC[s_cidn[s] * 64 + e]; }
      } else if (tid < 291) {
        int k = tid - 256;
        if (k < 5) pfv = (k == 0) ? vqc0_all[b * 128 + t + 1] : vqcC_all[s_cidn[k]];
        else if (k < 10) { int s = k - 5; pfkb = (s == 0) ? kb0_all[b * 128 + t + 1] : kbC_all[s_cidn[s]]; }
        else if (k < 20) pfs = tix_all[(bt0 + t) * RKK + k - 10];
        else if (k < 30) pfs = tmsk_all[(bt0 + t) * RKK + k - 20];
        else { int tn = (t + 1 < TST) ? t + 1 : TST - 1; pfs = cid_all[(b * 128 + tn + 1) * 5 + k - 30]; }
      }
      const uint4* xp = (const uint4*)s_h1pk[par] + jc * 5;
      float a0 = 0.f, a1 = 0.f, a2 = 0.f;
#pragma unroll
      for (int kk = 0; kk < 4; ++kk) {
        uint4 xk = xp[kk];
        uint4 w;
        w = wgt[0][kk]; a0 = fd2u(a0, w.x, xk.x); a0 = fd2u(a0, w.y, xk.y); a0 = fd2u(a0, w.z, xk.z); a0 = fd2u(a0, w.w, xk.w);
        w = wgt[1][kk]; a1 = fd2u(a1, w.x, xk.x); a1 = fd2u(a1, w.y, xk.y); a1 = fd2u(a1, w.z, xk.z); a1 = fd2u(a1, w.w, xk.w);
        w = wgt[2][kk]; a2 = fd2u(a2, w.x, xk.x); a2 = fd2u(a2, w.y, xk.y); a2 = fd2u(a2, w.z, xk.z); a2 = fd2u(a2, w.w, xk.w);
      }
      a0 += __shfl_down(a0, 2); a0 += __shfl_down(a0, 1);
      a1 += __shfl_down(a1, 2); a1 += __shfl_down(a1, 1);
      a2 += __shfl_down(a2, 2); a2 += __shfl_down(a2, 1);
      if (jc == 0) {
        float r = sigm(s_gi1[i] + a0 + s_bhh1[i]);
        float z = sigm(s_gi1[128 + i] + a1 + s_bhh1[128 + i]);
        float n = ftanh(s_gi1[256 + i] + r * (a2 + s_bhh1[256 + i]));
        float h1n = (1.f - z) * n + z * s_h1f[par][XI(i)];
        s_h1f[parn][XI(i)] = h1n;
        ((__fp16*)s_h1pk[parn])[PH(i)] = (__fp16)h1n;
      }
    }
    if (t >= 1) {
      if (tid < 440) {
        int p = tid >> 3, sub = tid & 7;
        int q = p / 5, s = p - q * 5;
        const unsigned* kpr = &s_Kq[parn][s * 66 + sub * 8];
        float a = 0.f;
        if (q == 0) {
          const unsigned* g2u = s_g2pk[parn];
          int e0 = sub * 16;
#pragma unroll
          for (int k = 0; k < 8; ++k) a = fd2u(a, kpr[k], g2u[PU(e0 + 2 * k)]);
        } else {
          const unsigned* ro = qph_pk + s_tix[q - 1] * 66;
#pragma unroll
          for (int k = 0; k < 8; ++k) a = fd2u(a, ro[sub * 8 + k], kpr[k]);
        }
        a += __shfl_down(a, 4);
        a += __shfl_down(a, 2);
        a += __shfl_down(a, 1);
        if (sub == 0) s_logit[p] = s_hm[q] ? (a + s_kb[parn][s]) : NEGV;
      } else if (wv == 7) {
        float pa = s_g2f[parn][XI(lane)] * wh_lo + s_g2f[parn][XI(64 + lane)] * wh_hi;
        for (int off = 32; off > 0; off >>= 1) pa += __shfl_down(pa, off);
        if (lane == 0) s_vh[0] = pa;
        if (lane >= 16 && lane < 26) s_vh[1 + lane - 16] = s_vhh[s_tix[lane - 16]];
      }
    }
    bar();

    // ==== Phase 2: GRU2(t) + softmax/out(t-1) + commits ====
    if (t < TST) {
      const uint4* xn = (const uint4*)s_h1pk[parn] + jc * 5;
      const uint4* xh = (t <= 1) ? ((const uint4*)s_h2pk + jc * 5)
                                 : ((const uint4*)s_g2pk[parn] + jc * 5);
      float a0 = 0.f, a1 = 0.f, a2 = 0.f, c0 = 0.f, c1 = 0.f, c2 = 0.f;
#pragma unroll
      for (int kk = 0; kk < 4; ++kk) {
        uint4 xa = xn[kk], xb = xh[kk];
        uint4 w;
        w = wgt[3][kk]; a0 = fd2u(a0, w.x, xa.x); a0 = fd2u(a0, w.y, xa.y); a0 = fd2u(a0, w.z, xa.z); a0 = fd2u(a0, w.w, xa.w);
        w = wgt[4][kk]; a1 = fd2u(a1, w.x, xa.x); a1 = fd2u(a1, w.y, xa.y); a1 = fd2u(a1, w.z, xa.z); a1 = fd2u(a1, w.w, xa.w);
        w = wgt[5][kk]; a2 = fd2u(a2, w.x, xa.x); a2 = fd2u(a2, w.y, xa.y); a2 = fd2u(a2, w.z, xa.z); a2 = fd2u(a2, w.w, xa.w);
        w = wgt[6][kk]; c0 = fd2u(c0, w.x, xb.x); c0 = fd2u(c0, w.y, xb.y); c0 = fd2u(c0, w.z, xb.z); c0 = fd2u(c0, w.w, xb.w);
        w = wgt[7][kk]; c1 = fd2u(c1, w.x, xb.x); c1 = fd2u(c1, w.y, xb.y); c1 = fd2u(c1, w.z, xb.z); c1 = fd2u(c1, w.w, xb.w);
        w = wgt[8][kk]; c2 = fd2u(c2, w.x, xb.x); c2 = fd2u(c2, w.y, xb.y); c2 = fd2u(c2, w.z, xb.z); c2 = fd2u(c2, w.w, xb.w);
      }
      a0 += __shfl_down(a0, 2); a0 += __shfl_down(a0, 1);
      a1 += __shfl_down(a1, 2); a1 += __shfl_down(a1, 1);
      a2 += __shfl_down(a2, 2); a2 += __shfl_down(a2, 1);
      c0 += __shfl_down(c0, 2); c0 += __shfl_down(c0, 1);
      c1 += __shfl_down(c1, 2); c1 += __shfl_down(c1, 1);
      c2 += __shfl_down(c2, 2); c2 += __shfl_down(c2, 1);
      if (jc == 0) {
        float r = sigm(a0 + s_bih2[i] + c0 + s_bhh2[i]);
        float z = sigm(a1 + s_bih2[128 + i] + c1 + s_bhh2[128 + i]);
        float n = ftanh(a2 + s_bih2[256 + i] + r * (c2 + s_bhh2[256 + i]));
        float h2old = (t <= 1) ? s_h2f[XI(i)] : s_g2f[parn][XI(i)];
        float g2v = (1.f - z) * n + z * h2old;
        s_g2f[par][XI(i)] = g2v;
        ((__fp16*)s_g2pk[par])[PH(i)] = (__fp16)g2v;
      }
    }
    if (t >= 1 && wv == 7) {
      float l = s_logit[lane];
      float m = l;
      for (int off = 32; off > 0; off >>= 1) m = fmaxf(m, __shfl_xor(m, off));
      float e = __expf(l - m);
      float v = 0.f;
      if (lane < 55) {
        int q = lane / 5, s = lane - q * 5;
        v = sigm(s_vh[q] + s_vqc[parn][s] + s_bw);
      }
      float num = e * v, den = e;
      for (int off = 32; off > 0; off >>= 1) { num += __shfl_xor(num, off); den += __shfl_xor(den, off); }
      if (lane == 0) out[b * SEQL + ((t - 1 == 0) ? 0 : t)] = num / den;
    }
    if (t < TST) {
      if (tid < 96) ((float4*)s_gi1)[tid] = pf4;
      else if (tid < 256) {
        int kx = tid - 96;
        { int s = kx >> 6, e = kx & 63; s_Kq[par][s * 66 + e] = pfu; }
        { int kx2 = kx + 160; int s = kx2 >> 6, e = kx2 & 63; s_Kq[par][s * 66 + e] = pfu2; }
      } else if (tid < 291) {
        int k = tid - 256;
        if (k < 5) s_vqc[par][k] = pfv;
        else if (k < 10) s_kb[par][k - 5] = pfkb;
        else if (k < 20) s_tix[k - 10] = pfs;
        else if (k < 30) s_hm[1 + k - 20] = pfs;
        else s_cidn[k - 30] = pfs;
      }
    }
    if (t >= 2 && tid >= 320 && tid < 384) {
      int k2 = tid - 320;
      qph_pk[(t - 1) * 66 + k2] = s_g2pk[parn][PU(2 * k2)];
    }
    if (t >= 2 && tid == 0) s_vhh[t - 1] = s_vh[0];
    bar();
  }
}

extern "C" void kernel_launch(void* const* d_in, const int* in_sizes, int n_in,
                              void* d_out, int out_size, void* d_ws, size_t ws_size,
                              hipStream_t stream) {
  (void)in_sizes; (void)n_in; (void)out_size; (void)ws_size;
  const int* qseq = (const int*)d_in[0];
  const int* rseq = (const int*)d_in[1];
  const int* mseq = (const int*)d_in[2];
  const int* qnbr = (const int*)d_in[3];
  const int* cnbr = (const int*)d_in[4];
  const int* qctab = (const int*)d_in[5];
  const float* Eq = (const float*)d_in[6];
  const float* Ec = (const float*)d_in[7];
  const float* Er = (const float*)d_in[8];
  const float* W_ih1 = (const float*)d_in[9];
  const float* W_hh1 = (const float*)d_in[10];
  const float* b_ih1 = (const float*)d_in[11];
  const float* b_hh1 = (const float*)d_in[12];
  const float* W_ih2 = (const float*)d_in[13];
  const float* W_hh2 = (const float*)d_in[14];
  const float* b_ih2 = (const float*)d_in[15];
  const float* b_hh2 = (const float*)d_in[16];
  const float* W_agg = (const float*)d_in[17];
  const float* b_agg = (const float*)d_in[18];
  const float* W_agg_last = (const float*)d_in[19];
  const float* b_agg_last = (const float*)d_in[20];
  const float* Wq = (const float*)d_in[21];
  const float* bq = (const float*)d_in[22];
  const float* Wk = (const float*)d_in[23];
  const float* bk = (const float*)d_in[24];
  const float* Ww = (const float*)d_in[25];
  const float* bw = (const float*)d_in[26];
  const float* h1i = (const float*)d_in[27];
  const float* h2i = (const float*)d_in[28];
  float* ws = (float*)d_ws;
  float* out = (float*)d_out;

  hipLaunchKernelGGL(k_prep, dim3(805), dim3(256), 0, stream,
                     W_hh1, W_ih2, W_hh2, W_agg, W_agg_last, W_ih1, Er,
                     Wq, Wk, bq, bk, ws);
  hipLaunchKernelGGL(k_concept, dim3(1000), dim3(128), 0, stream,
                     cnbr, Eq, Ec, b_agg, Ww, ws);
  hipLaunchKernelGGL(k_gram, dim3(256), dim3(256), 0, stream,
                     qseq, Eq, Ww, ws);
  hipLaunchKernelGGL(k_topk, dim3(BSZ * TST / 2), dim3(128), 0, stream,
                     qseq, qctab, ws);
  hipLaunchKernelGGL(k_agg, dim3(BSZ * 16), dim3(128), 0, stream,
                     qseq, rseq, mseq, qnbr, Eq, b_agg, b_agg_last, b_ih1, ws);
  hipLaunchKernelGGL(k_seq, dim3(BSZ), dim3(512), 0, stream,
                     b_hh1, b_ih2, b_hh2, Ww, bw, h1i, h2i, ws, out);
}